// Round 15
// baseline (97.452 us; speedup 1.0000x reference)
//
#include <hip/hip_runtime.h>
#include <hip/hip_bf16.h>

#define B_   2
#define T_   2048
#define D_   1024
#define NH_  16
#define NKV_ 4
#define HD_  64
#define E_   1536  // (NH + 2*NKV) * HD
#define LOG2E 1.4426950408889634f

typedef __attribute__((ext_vector_type(8))) __bf16 bf16x8;
typedef __attribute__((ext_vector_type(4))) __bf16 bf16x4;
typedef __attribute__((ext_vector_type(4))) float f32x4;
typedef __attribute__((ext_vector_type(16))) float f32x16;

// async global->LDS, 16B per lane. LDS dest = wave-uniform base + lane*16.
static __device__ __forceinline__ void gld_lds16(const unsigned short* g, unsigned short* l) {
  __builtin_amdgcn_global_load_lds(
      (const __attribute__((address_space(1))) unsigned int*)(unsigned long long)(const void*)g,
      (__attribute__((address_space(3))) unsigned int*)(unsigned int)(unsigned long long)(void*)l,
      16, 0, 0);
}

// raw hardware ops (avoid OCML guard sequences; args bounded, FTZ exact for us)
static __device__ __forceinline__ float fexp2(float x) {
  float r; asm("v_exp_f32 %0, %1" : "=v"(r) : "v"(x)); return r;
}
static __device__ __forceinline__ float fmax3(float a, float b, float c) {
  float r; asm("v_max3_f32 %0, %1, %2, %3" : "=v"(r) : "v"(a), "v"(b), "v"(c)); return r;
}
static __device__ __forceinline__ float frcp(float x) {
  float r; asm("v_rcp_f32 %0, %1" : "=v"(r) : "v"(x)); return r;
}

// counted-vmcnt barrier: loads stay in flight across the barrier (T3/T4, m201 pattern)
#define PIPE_BARRIER(N) {                                   \
  asm volatile("s_waitcnt vmcnt(" #N ")" ::: "memory");     \
  __builtin_amdgcn_s_barrier();                             \
  __builtin_amdgcn_sched_barrier(0); }

#define CVT8(dst, f0, f1) {                                                    \
  dst[0] = (__bf16)f0.x; dst[1] = (__bf16)f0.y;                               \
  dst[2] = (__bf16)f0.z; dst[3] = (__bf16)f0.w;                               \
  dst[4] = (__bf16)f1.x; dst[5] = (__bf16)f1.y;                               \
  dst[6] = (__bf16)f1.z; dst[7] = (__bf16)f1.w; }

// ---- fp32->bf16 convert, PRE-SWIZZLED: buf[n][c ^ 8*(n&7)] = src[n][c] ----
__global__ void k_convert_all(const float* __restrict__ x, const float* __restrict__ wq,
                              const float* __restrict__ wp,
                              unsigned short* __restrict__ xb, unsigned short* __restrict__ wqb,
                              unsigned short* __restrict__ wpb) {
  int i = blockIdx.x * blockDim.x + threadIdx.x;  // 851968 total groups of 8
  const float* src; unsigned short* dst; int j;
  if (i < 524288)      { src = x;  dst = xb;  j = i; }
  else if (i < 720896) { src = wq; dst = wqb; j = i - 524288; }
  else                 { src = wp; dst = wpb; j = i - 720896; }
  int n = j >> 7, c8 = (j & 127) * 8;
  const float4* p = (const float4*)(src + (size_t)n * 1024 + c8);
  float4 a = p[0], b = p[1];
  bf16x8 o; CVT8(o, a, b);
  *(bf16x8*)(dst + (size_t)n * 1024 + (c8 ^ ((n & 7) * 8))) = o;
}

// ---------------- QKV GEMM: 128x128 tile, 4 waves x 64x64, BK=64, 2-phase ------------
__global__ __launch_bounds__(256) void k_gemm_qkv(
    const unsigned short* __restrict__ A,   // pre-swizzled bf16 x
    const unsigned short* __restrict__ W,   // pre-swizzled bf16
    const float* __restrict__ cosT, const float* __restrict__ sinT,
    const float* __restrict__ v0,
    const float* __restrict__ vrl, const float* __restrict__ qks,
    unsigned short* __restrict__ qb, unsigned short* __restrict__ kb,
    unsigned short* __restrict__ vb) {
  __shared__ __align__(16) unsigned short As[2][128 * 64];
  __shared__ __align__(16) unsigned short Ws[2][128 * 64];
  int tid = threadIdx.x;
  int w = tid >> 6, l = tid & 63, lo = l & 15, hi = l >> 4;
  int wm = w >> 1, wn = w & 1;
  int f = blockIdx.y * 12 + blockIdx.x;           // 384 blocks, %8==0
  int f2 = (f & 7) * 48 + (f >> 3);               // XCD swizzle
  int bn = f2 % 12, bm = f2 / 12;
  int rsw = (lo & 7) * 8;                         // read-side swizzle

  const unsigned short* Ab = A + (size_t)bm * 128 * 1024;
  const unsigned short* Wb = W + (size_t)bn * 128 * 1024;

  f32x4 acc[4][4];
#pragma unroll
  for (int mi = 0; mi < 4; ++mi)
#pragma unroll
    for (int ni = 0; ni < 4; ++ni) acc[mi][ni] = (f32x4){0.f, 0.f, 0.f, 0.f};

#define STAGE(kt, buf) {                                                       \
  int k0 = (kt) * 64;                                                         \
  _Pragma("unroll") for (int ii = 0; ii < 4; ++ii) {                          \
    int sb = ii * 256 + tid;                                                  \
    gld_lds16(Ab + (size_t)(sb >> 3) * 1024 + k0 + (sb & 7) * 8,              \
              &As[buf][(sb & ~63) * 8]);                                      \
  }                                                                           \
  _Pragma("unroll") for (int ii = 0; ii < 4; ++ii) {                          \
    int sb = ii * 256 + tid;                                                  \
    gld_lds16(Wb + (size_t)(sb >> 3) * 1024 + k0 + (sb & 7) * 8,              \
              &Ws[buf][(sb & ~63) * 8]);                                      \
  } }

  STAGE(0, 0);
  __syncthreads();

  for (int kt = 0; kt < 16; ++kt) {
    int cur = kt & 1;
    bool pf = (kt + 1) < 16;
    if (pf) STAGE(kt + 1, cur ^ 1);
    __builtin_amdgcn_s_setprio(1);
#pragma unroll
    for (int kk = 0; kk < 2; ++kk) {
      int c0 = (kk * 32 + hi * 8) ^ rsw;
      bf16x8 af[4], wf[4];
#pragma unroll
      for (int mi = 0; mi < 4; ++mi)
        af[mi] = *(const bf16x8*)&As[cur][(wm * 64 + mi * 16 + lo) * 64 + c0];
#pragma unroll
      for (int ni = 0; ni < 4; ++ni)
        wf[ni] = *(const bf16x8*)&Ws[cur][(wn * 64 + ni * 16 + lo) * 64 + c0];
#pragma unroll
      for (int mi = 0; mi < 4; ++mi)
#pragma unroll
        for (int ni = 0; ni < 4; ++ni)
          acc[mi][ni] = __builtin_amdgcn_mfma_f32_16x16x32_bf16(af[mi], wf[ni], acc[mi][ni], 0, 0, 0);
    }
    __builtin_amdgcn_s_setprio(0);
    __syncthreads();
  }
#undef STAGE

  // epilogue: hg = 2*bn + wn = head group (0-15 q, 16-19 k, 20-23 v)
  int hg = bn * 2 + wn;
  if (hg < 20) {
    int isq = (hg < 16);
    int h = isq ? hg : hg - 16;
    float sc = isq ? (qks[h] * (LOG2E / 64.0f)) : 1.0f;
    unsigned short* base = isq ? qb : kb;
    int nheads = isq ? NH_ : NKV_;
#pragma unroll
    for (int mi = 0; mi < 4; ++mi) {
#pragma unroll
      for (int r = 0; r < 4; ++r) {
        int row = bm * 128 + wm * 64 + mi * 16 + hi * 4 + r;
        int b = row >> 11, t = row & 2047;
        float c = cosT[t * 16 + lo], s = sinT[t * 16 + lo];
        float a0 = acc[mi][0][r], a1 = acc[mi][1][r];
        __bf16* dp = (__bf16*)(base + ((size_t)(b * nheads + h) * T_ + t) * 64);
        int ts = isq ? 0 : (8 * (t & 7));  // K stored d-swizzled for attn LDS reads
        dp[lo ^ ts]        = (__bf16)((a0 * c - a1 * s) * sc);
        dp[(16 + lo) ^ ts] = (__bf16)((a0 * s + a1 * c) * sc);
        dp[(32 + lo) ^ ts] = (__bf16)(acc[mi][2][r] * sc);
        dp[(48 + lo) ^ ts] = (__bf16)(acc[mi][3][r] * sc);
      }
    }
  } else {
    int hv = hg - 20;
    float av[4];
#pragma unroll
    for (int j = 0; j < 4; ++j) av[j] = 1.0f / (1.0f + __expf(-vrl[hv * 4 + j]));
#pragma unroll
    for (int mi = 0; mi < 4; ++mi) {
      int t0g = bm * 128 + wm * 64 + mi * 16 + hi * 4;
      int b = t0g >> 11, t0 = t0g & 2047;
#pragma unroll
      for (int ni = 0; ni < 4; ++ni) {
        int d = ni * 16 + lo;
#pragma unroll
        for (int j = 0; j < 4; ++j) {
          float a = av[j], na = 1.0f - a;
          const float* v0p = v0 + ((size_t)(b * NH_ + hv * 4 + j) * T_ + t0) * 64 + d;
          bf16x4 vv;
#pragma unroll
          for (int r = 0; r < 4; ++r)
            vv[r] = (__bf16)(na * acc[mi][ni][r] + a * v0p[(size_t)r * 64]);
          // v^T store: [b][h][d][t], t swizzled within 64-block by 8*(d&7)
          *(bf16x4*)((unsigned short*)vb + ((size_t)(b * NH_ + hv * 4 + j) * 64 + d) * T_ +
                     (t0 ^ (8 * (lo & 7)))) = vv;
        }
      }
    }
  }
}

// ---------------- proj GEMM: 128x128 tile (+ fused v0 passthrough copy blocks) ----------
__global__ __launch_bounds__(256) void k_gemm_proj(
    const unsigned short* __restrict__ A,
    const unsigned short* __restrict__ W,
    const float* __restrict__ v0,
    float* __restrict__ C, float* __restrict__ out2) {
  __shared__ __align__(16) unsigned short As[2][128 * 64];
  __shared__ __align__(16) unsigned short Ws[2][128 * 64];
  int tid = threadIdx.x;

  if (blockIdx.y >= 32) {  // v0 passthrough: 128 blocks x 256 thr x 32 float4
    int idx = ((blockIdx.y - 32) * 8 + blockIdx.x) * 256 + tid;
    const float4* src = (const float4*)v0;
    float4* dst = (float4*)out2;
#pragma unroll
    for (int i = 0; i < 32; ++i) dst[idx + i * 32768] = src[idx + i * 32768];
    return;
  }

  int w = tid >> 6, l = tid & 63, lo = l & 15, hi = l >> 4;
  int wm = w >> 1, wn = w & 1;
  int f = blockIdx.y * 8 + blockIdx.x;  // 256 gemm blocks
  int f2 = (f & 7) * 32 + (f >> 3);
  int bn = f2 & 7, bm = f2 >> 3;
  int rsw = (lo & 7) * 8;

  const unsigned short* Ab = A + (size_t)bm * 128 * 1024;
  const unsigned short* Wb = W + (size_t)bn * 128 * 1024;

  f32x4 acc[4][4];
#pragma unroll
  for (int mi = 0; mi < 4; ++mi)
#pragma unroll
    for (int ni = 0; ni < 4; ++ni) acc[mi][ni] = (f32x4){0.f, 0.f, 0.f, 0.f};

#define STAGE(kt, buf) {                                                       \
  int k0 = (kt) * 64;                                                         \
  _Pragma("unroll") for (int ii = 0; ii < 4; ++ii) {                          \
    int sb = ii * 256 + tid;                                                  \
    gld_lds16(Ab + (size_t)(sb >> 3) * 1024 + k0 + (sb & 7) * 8,              \
              &As[buf][(sb & ~63) * 8]);                                      \
  }                                                                           \
  _Pragma("unroll") for (int ii = 0; ii < 4; ++ii) {                          \
    int sb = ii * 256 + tid;                                                  \
    gld_lds16(Wb + (size_t)(sb >> 3) * 1024 + k0 + (sb & 7) * 8,              \
              &Ws[buf][(sb & ~63) * 8]);                                      \
  } }

  STAGE(0, 0);
  __syncthreads();
  for (int kt = 0; kt < 16; ++kt) {
    int cur = kt & 1;
    bool pf = (kt + 1) < 16;
    if (pf) STAGE(kt + 1, cur ^ 1);
    __builtin_amdgcn_s_setprio(1);
#pragma unroll
    for (int kk = 0; kk < 2; ++kk) {
      int c0 = (kk * 32 + hi * 8) ^ rsw;
      bf16x8 af[4], wf[4];
#pragma unroll
      for (int mi = 0; mi < 4; ++mi)
        af[mi] = *(const bf16x8*)&As[cur][(wm * 64 + mi * 16 + lo) * 64 + c0];
#pragma unroll
      for (int ni = 0; ni < 4; ++ni)
        wf[ni] = *(const bf16x8*)&Ws[cur][(wn * 64 + ni * 16 + lo) * 64 + c0];
#pragma unroll
      for (int mi = 0; mi < 4; ++mi)
#pragma unroll
        for (int ni = 0; ni < 4; ++ni)
          acc[mi][ni] = __builtin_amdgcn_mfma_f32_16x16x32_bf16(af[mi], wf[ni], acc[mi][ni], 0, 0, 0);
    }
    __builtin_amdgcn_s_setprio(0);
    __syncthreads();
  }
#undef STAGE

#pragma unroll
  for (int mi = 0; mi < 4; ++mi) {
#pragma unroll
    for (int r = 0; r < 4; ++r) {
      int row = bm * 128 + wm * 64 + mi * 16 + hi * 4 + r;
      float* cp = C + (size_t)row * D_ + bn * 128 + wn * 64 + lo;
#pragma unroll
      for (int ni = 0; ni < 4; ++ni) cp[ni * 16] = acc[mi][ni][r];
    }
  }
}

// ---------------- flash attention: 32x32 MFMA, P via LDS (k-map agnostic), 8 waves ------
// wave w: st=w>>2 (state), wq=(w>>1)&1 (q half 32), kh=w&1 (key half 32).
static __device__ __forceinline__ void stage_kv8(const unsigned short* Kb, const unsigned short* Vb,
                                                 int kv0, int w, int l,
                                                 unsigned short* KsB, unsigned short* VsB) {
  gld_lds16(Kb + (size_t)kv0 * 64 + w * 512 + l * 8, KsB + w * 512);
  gld_lds16(Vb + (size_t)(w * 8 + (l >> 3)) * T_ + kv0 + (l & 7) * 8, VsB + w * 512);
}

__global__ __launch_bounds__(512, 2) void k_attn(const unsigned short* __restrict__ Q,
                                                 const unsigned short* __restrict__ Kp,
                                                 const unsigned short* __restrict__ Vtp,
                                                 unsigned short* __restrict__ Y) {
  // grid (NH, 16, B): h fast -> all p-blocks of one (h,b) share an XCD's L2.
  int p = blockIdx.y, h = blockIdx.x, b = blockIdx.z;
  if (b == 1) p = 15 - p;
  int tid = threadIdx.x;
  int w = tid >> 6, l = tid & 63;
  int l31 = l & 31, lh = l >> 5;
  int kh = w & 1, wq = (w >> 1) & 1, st = w >> 2;
  int kha = kh * 32;
  int qtA = p, qtB = 31 - p;
  int ntB = qtB + 1;  // >= 17
  int qt = st ? qtA : qtB;
  int q0w = qt * 64 + wq * 32;

  // SMEM: K[3][4096] | V[3][4096] | P[8][1024]  = 32768 shorts = 64 KB
  __shared__ __align__(16) unsigned short SMEM[32768];
  unsigned short* Kbase = SMEM;
  unsigned short* Vbase = SMEM + 3 * 4096;
  unsigned short* PsW   = SMEM + 6 * 4096 + w * 1024 + l31 * 32;  // [32q][32k] per wave

  const unsigned short* Qb = Q + ((size_t)(b * NH_ + h) * T_) * 64;
  const unsigned short* Kb = Kp + ((size_t)(b * NKV_ + (h >> 2)) * T_) * 64;
  const unsigned short* Vb = Vtp + ((size_t)(b * NH_ + h) * 64) * T_;

  // Q B-frag loads (contiguous-d; k-map cancels against K A-frag loads)
  bf16x8 qf[4];
#pragma unroll
  for (int ds = 0; ds < 4; ++ds)
    qf[ds] = *(const bf16x8*)(Qb + (size_t)(q0w + l31) * 64 + ds * 16 + lh * 8);

  int key = kha + l31;
  int kbase = key * 64, ksw = 8 * (key & 7);
  int vb0 = l31 * 64, vsw = 8 * (l31 & 7);          // d0 = l31; d1 = 32+l31 (same &7)
  int vb1 = (32 + l31) * 64;
  int psw = 8 * (l31 & 3);                          // P bank swizzle (q-based)

  f32x16 y0{}, y1{};
  float m = -INFINITY, lsum = 0.f;

  stage_kv8(Kb, Vb, 0, w, l, Kbase, Vbase);
  stage_kv8(Kb, Vb, 64, w, l, Kbase + 4096, Vbase + 4096);
  int cur = 0, wbuf = 2;

  for (int kt = 0; kt < ntB; ++kt) {
    if (kt + 1 < ntB) PIPE_BARRIER(2) else PIPE_BARRIER(0);
    if (kt + 2 < ntB) stage_kv8(Kb, Vb, (kt + 2) * 64, w, l, Kbase + wbuf * 4096, Vbase + wbuf * 4096);

    bool act = (kt < qt) || (kt == qt && !(kh == 1 && wq == 0));
    if (act) {
      int kv0 = kt * 64;
      const unsigned short* KsC = Kbase + cur * 4096;
      const unsigned short* VsC = Vbase + cur * 4096;

      // S^T = mfma(K, Q): col q = l31, row key (C/D map) = kha + (i&3)+8*(i>>2)+4*lh
      f32x16 s{};
      __builtin_amdgcn_s_setprio(1);
#pragma unroll
      for (int ds = 0; ds < 4; ++ds) {
        bf16x8 kf = *(const bf16x8*)&KsC[kbase + ((ds * 16 + lh * 8) ^ ksw)];
        s = __builtin_amdgcn_mfma_f32_32x32x16_bf16(kf, qf[ds], s, 0, 0, 0);
      }
      __builtin_amdgcn_s_setprio(0);

      if (kt == qt) {  // diagonal: mask key > q
        int qg = q0w + l31;
#pragma unroll
        for (int i = 0; i < 16; ++i) {
          int keyg = kv0 + kha + (i & 3) + 8 * (i >> 2) + 4 * lh;
          if (keyg > qg) s[i] = -1e30f;
        }
      }

      // online softmax (defer-max THR=8); per-q split across lanes l / l+32
      float pm = fmax3(s[0], s[1], s[2]);
      pm = fmax3(pm, s[3], s[4]);
      pm = fmax3(pm, s[5], s[6]);
      pm = fmax3(pm, s[7], s[8]);
      pm = fmax3(pm, s[9], s[10]);
      pm = fmax3(pm, s[11], s[12]);
      pm = fmax3(pm, s[13], s[14]);
      pm = fmaxf(pm, s[15]);
      pm = fmaxf(pm, __shfl_xor(pm, 32));  // per-q max (both lane halves)
      if (!__all(pm <= m + 8.0f)) {
        float mnew = fmaxf(m, pm);
        float sc = fexp2(m - mnew);
        lsum *= sc;
#pragma unroll
        for (int i = 0; i < 16; ++i) { y0[i] *= sc; y1[i] *= sc; }
        m = mnew;
      }
      float rs = 0.f;
#pragma unroll
      for (int i = 0; i < 16; ++i) {
        float pv = fexp2(s[i] - m);
        s[i] = pv;
        rs += pv;
      }
      lsum += rs;

      // P -> LDS in LINEAR key layout: reg group g holds keys 8g+4lh+0..3
#pragma unroll
      for (int g = 0; g < 4; ++g) {
        bf16x4 pk;
        pk[0] = (__bf16)s[g * 4 + 0]; pk[1] = (__bf16)s[g * 4 + 1];
        pk[2] = (__bf16)s[g * 4 + 2]; pk[3] = (__bf16)s[g * 4 + 3];
        *(bf16x4*)(PsW + ((8 * g + 4 * lh) ^ psw)) = pk;
      }

      // PV: y^T[d][q] = mfma(V^T, P); both operands read with contiguous-k -> map cancels
      __builtin_amdgcn_s_setprio(1);
#pragma unroll
      for (int kw = 0; kw < 2; ++kw) {
        bf16x8 pb = *(const bf16x8*)(PsW + ((kw * 16 + lh * 8) ^ psw));
        bf16x8 va0 = *(const bf16x8*)&VsC[vb0 + ((kha + kw * 16 + lh * 8) ^ vsw)];
        y0 = __builtin_amdgcn_mfma_f32_32x32x16_bf16(va0, pb, y0, 0, 0, 0);
        bf16x8 va1 = *(const bf16x8*)&VsC[vb1 + ((kha + kw * 16 + lh * 8) ^ vsw)];
        y1 = __builtin_amdgcn_mfma_f32_32x32x16_bf16(va1, pb, y1, 0, 0, 0);
      }
      __builtin_amdgcn_s_setprio(0);
    }

    cur = (cur == 2) ? 0 : cur + 1;
    wbuf = (wbuf == 2) ? 0 : wbuf + 1;
  }

  // ---- combine key-half pairs (kh=0 owns output), write pre-swizzled y ----
  __syncthreads();  // all compute done; reuse SMEM as float buffer (36 KB < 64 KB)
  float lt = lsum + __shfl_xor(lsum, 32);
  float* buf = (float*)SMEM;
  int slot = ((st * 2 + wq) * 64 + l) * 36;
  if (kh) {
#pragma unroll
    for (int i = 0; i < 16; ++i) { buf[slot + i] = y0[i]; buf[slot + 16 + i] = y1[i]; }
    buf[slot + 32] = m;
    buf[slot + 33] = lt;
  }
  __syncthreads();
  if (!kh) {
    float m1 = buf[slot + 32], l1 = buf[slot + 33];
    float M = fmaxf(m, m1);
    float f0 = fexp2(m - M), f1 = fexp2(m1 - M);
    float inv = frcp(lt * f0 + l1 * f1);
    int t = q0w + l31;
    int sw = 8 * (t & 7);
    __bf16* yp = (__bf16*)(Y + ((size_t)(b * T_ + t)) * D_ + h * 64);
#pragma unroll
    for (int dB = 0; dB < 2; ++dB) {
#pragma unroll
      for (int g = 0; g < 4; ++g) {
        int dbase = dB * 32 + g * 8 + 4 * lh;  // d rows for regs g*4+r: r contiguous
        bf16x4 o;
#pragma unroll
        for (int r = 0; r < 4; ++r) {
          float self = dB ? y1[g * 4 + r] : y0[g * 4 + r];
          float other = buf[slot + dB * 16 + g * 4 + r];
          o[r] = (__bf16)((self * f0 + other * f1) * inv);
        }
        *(bf16x4*)(yp + (dbase ^ sw)) = o;
      }
    }
  }
}

extern "C" void kernel_launch(void* const* d_in, const int* in_sizes, int n_in,
                              void* d_out, int out_size, void* d_ws, size_t ws_size,
                              hipStream_t stream) {
  const float* x     = (const float*)d_in[0];
  const float* cosT  = (const float*)d_in[1];
  const float* sinT  = (const float*)d_in[2];
  const float* v0    = (const float*)d_in[3];
  const float* Wqkv  = (const float*)d_in[4];
  const float* Wproj = (const float*)d_in[5];
  const float* vrl   = (const float*)d_in[6];
  const float* qks   = (const float*)d_in[7];
  float* out = (float*)d_out;

  char* ws = (char*)d_ws;
  unsigned short* xb     = (unsigned short*)ws;                   //  8388608 B (pre-swizzled)
  unsigned short* wqkvb  = (unsigned short*)(ws + 8388608);       //  3145728 B (pre-swizzled)
  unsigned short* wprojb = (unsigned short*)(ws + 11534336);      //  2097152 B (pre-swizzled)
  unsigned short* qb     = (unsigned short*)(ws + 13631488);      //  8388608 B
  unsigned short* kb     = (unsigned short*)(ws + 22020096);      //  2097152 B (d-swizzled)
  unsigned short* vb     = (unsigned short*)(ws + 24117248);      //  8388608 B (V^T swizzled)
  unsigned short* yb     = (unsigned short*)(ws + 32505856);      //  8388608 B (pre-swizzled)

  k_convert_all<<<3328, 256, 0, stream>>>(x, Wqkv, Wproj, xb, wqkvb, wprojb);

  k_gemm_qkv<<<dim3(12, 32), 256, 0, stream>>>(xb, wqkvb, cosT, sinT, v0, vrl, qks, qb, kb, vb);

  k_attn<<<dim3(NH_, 16, B_), 512, 0, stream>>>(qb, kb, vb, yb);

  k_gemm_proj<<<dim3(8, 48), 256, 0, stream>>>(yb, wprojb, v0, out, out + 4194304);
}

// Round 16
// 94.775 us; speedup vs baseline: 1.0282x; 1.0282x over previous
//
#include <hip/hip_runtime.h>
#include <hip/hip_bf16.h>

#define B_   2
#define T_   2048
#define D_   1024
#define NH_  16
#define NKV_ 4
#define HD_  64
#define E_   1536  // (NH + 2*NKV) * HD
#define LOG2E 1.4426950408889634f

typedef __attribute__((ext_vector_type(8))) __bf16 bf16x8;
typedef __attribute__((ext_vector_type(4))) __bf16 bf16x4;
typedef __attribute__((ext_vector_type(4))) float f32x4;
typedef __attribute__((ext_vector_type(16))) float f32x16;

// async global->LDS, 16B per lane. LDS dest = wave-uniform base + lane*16.
static __device__ __forceinline__ void gld_lds16(const unsigned short* g, unsigned short* l) {
  __builtin_amdgcn_global_load_lds(
      (const __attribute__((address_space(1))) unsigned int*)(unsigned long long)(const void*)g,
      (__attribute__((address_space(3))) unsigned int*)(unsigned int)(unsigned long long)(void*)l,
      16, 0, 0);
}

// raw hardware ops (avoid OCML guard sequences; args bounded, FTZ exact for us)
static __device__ __forceinline__ float fexp2(float x) {
  float r; asm("v_exp_f32 %0, %1" : "=v"(r) : "v"(x)); return r;
}
static __device__ __forceinline__ float fmax3(float a, float b, float c) {
  float r; asm("v_max3_f32 %0, %1, %2, %3" : "=v"(r) : "v"(a), "v"(b), "v"(c)); return r;
}
static __device__ __forceinline__ float frcp(float x) {
  float r; asm("v_rcp_f32 %0, %1" : "=v"(r) : "v"(x)); return r;
}

// counted-vmcnt barrier: loads stay in flight across the barrier (T3/T4, m201 pattern)
#define PIPE_BARRIER(N) {                                   \
  asm volatile("s_waitcnt vmcnt(" #N ")" ::: "memory");     \
  __builtin_amdgcn_s_barrier();                             \
  __builtin_amdgcn_sched_barrier(0); }

#define CVT8(dst, f0, f1) {                                                    \
  dst[0] = (__bf16)f0.x; dst[1] = (__bf16)f0.y;                               \
  dst[2] = (__bf16)f0.z; dst[3] = (__bf16)f0.w;                               \
  dst[4] = (__bf16)f1.x; dst[5] = (__bf16)f1.y;                               \
  dst[6] = (__bf16)f1.z; dst[7] = (__bf16)f1.w; }

// ---- fp32->bf16 convert, PRE-SWIZZLED: buf[n][c ^ 8*(n&7)] = src[n][c] ----
__global__ void k_convert_all(const float* __restrict__ x, const float* __restrict__ wq,
                              const float* __restrict__ wp,
                              unsigned short* __restrict__ xb, unsigned short* __restrict__ wqb,
                              unsigned short* __restrict__ wpb) {
  int i = blockIdx.x * blockDim.x + threadIdx.x;  // 851968 total groups of 8
  const float* src; unsigned short* dst; int j;
  if (i < 524288)      { src = x;  dst = xb;  j = i; }
  else if (i < 720896) { src = wq; dst = wqb; j = i - 524288; }
  else                 { src = wp; dst = wpb; j = i - 720896; }
  int n = j >> 7, c8 = (j & 127) * 8;
  const float4* p = (const float4*)(src + (size_t)n * 1024 + c8);
  float4 a = p[0], b = p[1];
  bf16x8 o; CVT8(o, a, b);
  *(bf16x8*)(dst + (size_t)n * 1024 + (c8 ^ ((n & 7) * 8))) = o;
}

// ---------------- QKV GEMM: 128x128 tile, 4 waves x 64x64, BK=64, 2-phase ------------
__global__ __launch_bounds__(256) void k_gemm_qkv(
    const unsigned short* __restrict__ A,   // pre-swizzled bf16 x
    const unsigned short* __restrict__ W,   // pre-swizzled bf16
    const float* __restrict__ cosT, const float* __restrict__ sinT,
    const float* __restrict__ v0,
    const float* __restrict__ vrl, const float* __restrict__ qks,
    unsigned short* __restrict__ qb, unsigned short* __restrict__ kb,
    unsigned short* __restrict__ vb) {
  __shared__ __align__(16) unsigned short As[2][128 * 64];
  __shared__ __align__(16) unsigned short Ws[2][128 * 64];
  int tid = threadIdx.x;
  int w = tid >> 6, l = tid & 63, lo = l & 15, hi = l >> 4;
  int wm = w >> 1, wn = w & 1;
  int f = blockIdx.y * 12 + blockIdx.x;           // 384 blocks, %8==0
  int f2 = (f & 7) * 48 + (f >> 3);               // XCD swizzle
  int bn = f2 % 12, bm = f2 / 12;
  int rsw = (lo & 7) * 8;                         // read-side swizzle

  const unsigned short* Ab = A + (size_t)bm * 128 * 1024;
  const unsigned short* Wb = W + (size_t)bn * 128 * 1024;

  f32x4 acc[4][4];
#pragma unroll
  for (int mi = 0; mi < 4; ++mi)
#pragma unroll
    for (int ni = 0; ni < 4; ++ni) acc[mi][ni] = (f32x4){0.f, 0.f, 0.f, 0.f};

#define STAGE(kt, buf) {                                                       \
  int k0 = (kt) * 64;                                                         \
  _Pragma("unroll") for (int ii = 0; ii < 4; ++ii) {                          \
    int sb = ii * 256 + tid;                                                  \
    gld_lds16(Ab + (size_t)(sb >> 3) * 1024 + k0 + (sb & 7) * 8,              \
              &As[buf][(sb & ~63) * 8]);                                      \
  }                                                                           \
  _Pragma("unroll") for (int ii = 0; ii < 4; ++ii) {                          \
    int sb = ii * 256 + tid;                                                  \
    gld_lds16(Wb + (size_t)(sb >> 3) * 1024 + k0 + (sb & 7) * 8,              \
              &Ws[buf][(sb & ~63) * 8]);                                      \
  } }

  STAGE(0, 0);
  __syncthreads();

  for (int kt = 0; kt < 16; ++kt) {
    int cur = kt & 1;
    bool pf = (kt + 1) < 16;
    if (pf) STAGE(kt + 1, cur ^ 1);
    __builtin_amdgcn_s_setprio(1);
#pragma unroll
    for (int kk = 0; kk < 2; ++kk) {
      int c0 = (kk * 32 + hi * 8) ^ rsw;
      bf16x8 af[4], wf[4];
#pragma unroll
      for (int mi = 0; mi < 4; ++mi)
        af[mi] = *(const bf16x8*)&As[cur][(wm * 64 + mi * 16 + lo) * 64 + c0];
#pragma unroll
      for (int ni = 0; ni < 4; ++ni)
        wf[ni] = *(const bf16x8*)&Ws[cur][(wn * 64 + ni * 16 + lo) * 64 + c0];
#pragma unroll
      for (int mi = 0; mi < 4; ++mi)
#pragma unroll
        for (int ni = 0; ni < 4; ++ni)
          acc[mi][ni] = __builtin_amdgcn_mfma_f32_16x16x32_bf16(af[mi], wf[ni], acc[mi][ni], 0, 0, 0);
    }
    __builtin_amdgcn_s_setprio(0);
    __syncthreads();
  }
#undef STAGE

  // epilogue: hg = 2*bn + wn = head group (0-15 q, 16-19 k, 20-23 v)
  int hg = bn * 2 + wn;
  if (hg < 20) {
    int isq = (hg < 16);
    int h = isq ? hg : hg - 16;
    float sc = isq ? (qks[h] * (LOG2E / 64.0f)) : 1.0f;
    unsigned short* base = isq ? qb : kb;
    int nheads = isq ? NH_ : NKV_;
#pragma unroll
    for (int mi = 0; mi < 4; ++mi) {
#pragma unroll
      for (int r = 0; r < 4; ++r) {
        int row = bm * 128 + wm * 64 + mi * 16 + hi * 4 + r;
        int b = row >> 11, t = row & 2047;
        float c = cosT[t * 16 + lo], s = sinT[t * 16 + lo];
        float a0 = acc[mi][0][r], a1 = acc[mi][1][r];
        __bf16* dp = (__bf16*)(base + ((size_t)(b * nheads + h) * T_ + t) * 64);
        int ts = isq ? 0 : (8 * (t & 7));  // K stored d-swizzled for attn LDS reads
        dp[lo ^ ts]        = (__bf16)((a0 * c - a1 * s) * sc);
        dp[(16 + lo) ^ ts] = (__bf16)((a0 * s + a1 * c) * sc);
        dp[(32 + lo) ^ ts] = (__bf16)(acc[mi][2][r] * sc);
        dp[(48 + lo) ^ ts] = (__bf16)(acc[mi][3][r] * sc);
      }
    }
  } else {
    int hv = hg - 20;
    float av[4];
#pragma unroll
    for (int j = 0; j < 4; ++j) av[j] = 1.0f / (1.0f + __expf(-vrl[hv * 4 + j]));
#pragma unroll
    for (int mi = 0; mi < 4; ++mi) {
      int t0g = bm * 128 + wm * 64 + mi * 16 + hi * 4;
      int b = t0g >> 11, t0 = t0g & 2047;
#pragma unroll
      for (int ni = 0; ni < 4; ++ni) {
        int d = ni * 16 + lo;
#pragma unroll
        for (int j = 0; j < 4; ++j) {
          float a = av[j], na = 1.0f - a;
          const float* v0p = v0 + ((size_t)(b * NH_ + hv * 4 + j) * T_ + t0) * 64 + d;
          bf16x4 vv;
#pragma unroll
          for (int r = 0; r < 4; ++r)
            vv[r] = (__bf16)(na * acc[mi][ni][r] + a * v0p[(size_t)r * 64]);
          // v^T store: [b][h][d][t], t swizzled within 64-block by 8*(d&7)
          *(bf16x4*)((unsigned short*)vb + ((size_t)(b * NH_ + hv * 4 + j) * 64 + d) * T_ +
                     (t0 ^ (8 * (lo & 7)))) = vv;
        }
      }
    }
  }
}

// ---------------- proj GEMM: 128x128 tile (+ fused v0 passthrough copy blocks) ----------
__global__ __launch_bounds__(256) void k_gemm_proj(
    const unsigned short* __restrict__ A,
    const unsigned short* __restrict__ W,
    const float* __restrict__ v0,
    float* __restrict__ C, float* __restrict__ out2) {
  __shared__ __align__(16) unsigned short As[2][128 * 64];
  __shared__ __align__(16) unsigned short Ws[2][128 * 64];
  int tid = threadIdx.x;

  if (blockIdx.y >= 32) {  // v0 passthrough: 128 blocks x 256 thr x 32 float4
    int idx = ((blockIdx.y - 32) * 8 + blockIdx.x) * 256 + tid;
    const float4* src = (const float4*)v0;
    float4* dst = (float4*)out2;
#pragma unroll
    for (int i = 0; i < 32; ++i) dst[idx + i * 32768] = src[idx + i * 32768];
    return;
  }

  int w = tid >> 6, l = tid & 63, lo = l & 15, hi = l >> 4;
  int wm = w >> 1, wn = w & 1;
  int f = blockIdx.y * 8 + blockIdx.x;  // 256 gemm blocks
  int f2 = (f & 7) * 32 + (f >> 3);
  int bn = f2 & 7, bm = f2 >> 3;
  int rsw = (lo & 7) * 8;

  const unsigned short* Ab = A + (size_t)bm * 128 * 1024;
  const unsigned short* Wb = W + (size_t)bn * 128 * 1024;

  f32x4 acc[4][4];
#pragma unroll
  for (int mi = 0; mi < 4; ++mi)
#pragma unroll
    for (int ni = 0; ni < 4; ++ni) acc[mi][ni] = (f32x4){0.f, 0.f, 0.f, 0.f};

#define STAGE(kt, buf) {                                                       \
  int k0 = (kt) * 64;                                                         \
  _Pragma("unroll") for (int ii = 0; ii < 4; ++ii) {                          \
    int sb = ii * 256 + tid;                                                  \
    gld_lds16(Ab + (size_t)(sb >> 3) * 1024 + k0 + (sb & 7) * 8,              \
              &As[buf][(sb & ~63) * 8]);                                      \
  }                                                                           \
  _Pragma("unroll") for (int ii = 0; ii < 4; ++ii) {                          \
    int sb = ii * 256 + tid;                                                  \
    gld_lds16(Wb + (size_t)(sb >> 3) * 1024 + k0 + (sb & 7) * 8,              \
              &Ws[buf][(sb & ~63) * 8]);                                      \
  } }

  STAGE(0, 0);
  __syncthreads();
  for (int kt = 0; kt < 16; ++kt) {
    int cur = kt & 1;
    bool pf = (kt + 1) < 16;
    if (pf) STAGE(kt + 1, cur ^ 1);
    __builtin_amdgcn_s_setprio(1);
#pragma unroll
    for (int kk = 0; kk < 2; ++kk) {
      int c0 = (kk * 32 + hi * 8) ^ rsw;
      bf16x8 af[4], wf[4];
#pragma unroll
      for (int mi = 0; mi < 4; ++mi)
        af[mi] = *(const bf16x8*)&As[cur][(wm * 64 + mi * 16 + lo) * 64 + c0];
#pragma unroll
      for (int ni = 0; ni < 4; ++ni)
        wf[ni] = *(const bf16x8*)&Ws[cur][(wn * 64 + ni * 16 + lo) * 64 + c0];
#pragma unroll
      for (int mi = 0; mi < 4; ++mi)
#pragma unroll
        for (int ni = 0; ni < 4; ++ni)
          acc[mi][ni] = __builtin_amdgcn_mfma_f32_16x16x32_bf16(af[mi], wf[ni], acc[mi][ni], 0, 0, 0);
    }
    __builtin_amdgcn_s_setprio(0);
    __syncthreads();
  }
#undef STAGE

#pragma unroll
  for (int mi = 0; mi < 4; ++mi) {
#pragma unroll
    for (int r = 0; r < 4; ++r) {
      int row = bm * 128 + wm * 64 + mi * 16 + hi * 4 + r;
      float* cp = C + (size_t)row * D_ + bn * 128 + wn * 64 + lo;
#pragma unroll
      for (int ni = 0; ni < 4; ++ni) cp[ni * 16] = acc[mi][ni][r];
    }
  }
}

// ---------------- flash attention: 32x32 MFMA, P via LDS stride-40 rows, 8 waves ------
// wave w: st=w>>2 (state), wq=(w>>1)&1 (q half 32), kh=w&1 (key half 32).
static __device__ __forceinline__ void stage_kv8(const unsigned short* Kb, const unsigned short* Vb,
                                                 int kv0, int w, int l,
                                                 unsigned short* KsB, unsigned short* VsB) {
  gld_lds16(Kb + (size_t)kv0 * 64 + w * 512 + l * 8, KsB + w * 512);
  gld_lds16(Vb + (size_t)(w * 8 + (l >> 3)) * T_ + kv0 + (l & 7) * 8, VsB + w * 512);
}

#define PSTRIDE 40  // shorts per P row: 80B, 16B-aligned, q*20 mod 32 spreads all banks

__global__ __launch_bounds__(512, 2) void k_attn(const unsigned short* __restrict__ Q,
                                                 const unsigned short* __restrict__ Kp,
                                                 const unsigned short* __restrict__ Vtp,
                                                 unsigned short* __restrict__ Y) {
  // grid (NH, 16, B): h fast -> all p-blocks of one (h,b) share an XCD's L2.
  int p = blockIdx.y, h = blockIdx.x, b = blockIdx.z;
  if (b == 1) p = 15 - p;
  int tid = threadIdx.x;
  int w = tid >> 6, l = tid & 63;
  int l31 = l & 31, lh = l >> 5;
  int kh = w & 1, wq = (w >> 1) & 1, st = w >> 2;
  int kha = kh * 32;
  int qtA = p, qtB = 31 - p;
  int ntB = qtB + 1;  // >= 17
  int qt = st ? qtA : qtB;
  int q0w = qt * 64 + wq * 32;

  // SMEM: K[3][4096] | V[3][4096] | P[8][32*PSTRIDE]  = 34816 shorts = 68 KB
  __shared__ __align__(16) unsigned short SMEM[6 * 4096 + 8 * 32 * PSTRIDE];
  unsigned short* Kbase = SMEM;
  unsigned short* Vbase = SMEM + 3 * 4096;
  unsigned short* PsW   = SMEM + 6 * 4096 + w * 32 * PSTRIDE + l31 * PSTRIDE;

  const unsigned short* Qb = Q + ((size_t)(b * NH_ + h) * T_) * 64;
  const unsigned short* Kb = Kp + ((size_t)(b * NKV_ + (h >> 2)) * T_) * 64;
  const unsigned short* Vb = Vtp + ((size_t)(b * NH_ + h) * 64) * T_;

  // Q B-frag loads (contiguous-d; k-map cancels against K A-frag loads)
  bf16x8 qf[4];
#pragma unroll
  for (int ds = 0; ds < 4; ++ds)
    qf[ds] = *(const bf16x8*)(Qb + (size_t)(q0w + l31) * 64 + ds * 16 + lh * 8);

  int key = kha + l31;
  int kbase = key * 64, ksw = 8 * (key & 7);
  int vb0 = l31 * 64, vsw = 8 * (l31 & 7);          // d0 = l31; d1 = 32+l31 (same &7)
  int vb1 = (32 + l31) * 64;

  f32x16 y0{}, y1{};
  float m = -INFINITY, lsum = 0.f;

  stage_kv8(Kb, Vb, 0, w, l, Kbase, Vbase);
  stage_kv8(Kb, Vb, 64, w, l, Kbase + 4096, Vbase + 4096);
  int cur = 0, wbuf = 2;

  for (int kt = 0; kt < ntB; ++kt) {
    if (kt + 1 < ntB) PIPE_BARRIER(2) else PIPE_BARRIER(0);
    if (kt + 2 < ntB) stage_kv8(Kb, Vb, (kt + 2) * 64, w, l, Kbase + wbuf * 4096, Vbase + wbuf * 4096);

    bool act = (kt < qt) || (kt == qt && !(kh == 1 && wq == 0));
    if (act) {
      int kv0 = kt * 64;
      const unsigned short* KsC = Kbase + cur * 4096;
      const unsigned short* VsC = Vbase + cur * 4096;

      // S^T = mfma(K, Q): col q = l31, row key (C/D map) = kha + (i&3)+8*(i>>2)+4*lh
      f32x16 s{};
      __builtin_amdgcn_s_setprio(1);
#pragma unroll
      for (int ds = 0; ds < 4; ++ds) {
        bf16x8 kf = *(const bf16x8*)&KsC[kbase + ((ds * 16 + lh * 8) ^ ksw)];
        s = __builtin_amdgcn_mfma_f32_32x32x16_bf16(kf, qf[ds], s, 0, 0, 0);
      }
      __builtin_amdgcn_s_setprio(0);

      if (kt == qt) {  // diagonal: mask key > q
        int qg = q0w + l31;
#pragma unroll
        for (int i = 0; i < 16; ++i) {
          int keyg = kv0 + kha + (i & 3) + 8 * (i >> 2) + 4 * lh;
          if (keyg > qg) s[i] = -1e30f;
        }
      }

      // online softmax (defer-max THR=8); per-q split across lanes l / l+32
      float pm = fmax3(s[0], s[1], s[2]);
      pm = fmax3(pm, s[3], s[4]);
      pm = fmax3(pm, s[5], s[6]);
      pm = fmax3(pm, s[7], s[8]);
      pm = fmax3(pm, s[9], s[10]);
      pm = fmax3(pm, s[11], s[12]);
      pm = fmax3(pm, s[13], s[14]);
      pm = fmaxf(pm, s[15]);
      pm = fmaxf(pm, __shfl_xor(pm, 32));  // per-q max (both lane halves)
      if (!__all(pm <= m + 8.0f)) {
        float mnew = fmaxf(m, pm);
        float sc = fexp2(m - mnew);
        lsum *= sc;
#pragma unroll
        for (int i = 0; i < 16; ++i) { y0[i] *= sc; y1[i] *= sc; }
        m = mnew;
      }
      float rs = 0.f;
#pragma unroll
      for (int i = 0; i < 16; ++i) {
        float pv = fexp2(s[i] - m);
        s[i] = pv;
        rs += pv;
      }
      lsum += rs;

      // P -> LDS in LINEAR key layout: reg group g holds keys 8g+4lh+0..3
#pragma unroll
      for (int g = 0; g < 4; ++g) {
        bf16x4 pk;
        pk[0] = (__bf16)s[g * 4 + 0]; pk[1] = (__bf16)s[g * 4 + 1];
        pk[2] = (__bf16)s[g * 4 + 2]; pk[3] = (__bf16)s[g * 4 + 3];
        *(bf16x4*)(PsW + 8 * g + 4 * lh) = pk;
      }

      // PV: y^T[d][q] = mfma(V^T, P); both operands read with contiguous-k -> map cancels
      __builtin_amdgcn_s_setprio(1);
#pragma unroll
      for (int kw = 0; kw < 2; ++kw) {
        bf16x8 pb = *(const bf16x8*)(PsW + kw * 16 + lh * 8);
        bf16x8 va0 = *(const bf16x8*)&VsC[vb0 + ((kha + kw * 16 + lh * 8) ^ vsw)];
        y0 = __builtin_amdgcn_mfma_f32_32x32x16_bf16(va0, pb, y0, 0, 0, 0);
        bf16x8 va1 = *(const bf16x8*)&VsC[vb1 + ((kha + kw * 16 + lh * 8) ^ vsw)];
        y1 = __builtin_amdgcn_mfma_f32_32x32x16_bf16(va1, pb, y1, 0, 0, 0);
      }
      __builtin_amdgcn_s_setprio(0);
    }

    cur = (cur == 2) ? 0 : cur + 1;
    wbuf = (wbuf == 2) ? 0 : wbuf + 1;
  }

  // ---- combine key-half pairs (kh=0 owns output), write pre-swizzled y ----
  __syncthreads();  // all compute done; reuse SMEM as float buffer (36 KB < 68 KB)
  float lt = lsum + __shfl_xor(lsum, 32);
  float* buf = (float*)SMEM;
  int slot = ((st * 2 + wq) * 64 + l) * 36;
  if (kh) {
#pragma unroll
    for (int i = 0; i < 16; ++i) { buf[slot + i] = y0[i]; buf[slot + 16 + i] = y1[i]; }
    buf[slot + 32] = m;
    buf[slot + 33] = lt;
  }
  __syncthreads();
  if (!kh) {
    float m1 = buf[slot + 32], l1 = buf[slot + 33];
    float M = fmaxf(m, m1);
    float f0 = fexp2(m - M), f1 = fexp2(m1 - M);
    float inv = frcp(lt * f0 + l1 * f1);
    int t = q0w + l31;
    int sw = 8 * (t & 7);
    __bf16* yp = (__bf16*)(Y + ((size_t)(b * T_ + t)) * D_ + h * 64);
#pragma unroll
    for (int dB = 0; dB < 2; ++dB) {
#pragma unroll
      for (int g = 0; g < 4; ++g) {
        int dbase = dB * 32 + g * 8 + 4 * lh;  // d rows for regs g*4+r: r contiguous
        bf16x4 o;
#pragma unroll
        for (int r = 0; r < 4; ++r) {
          float self = dB ? y1[g * 4 + r] : y0[g * 4 + r];
          float other = buf[slot + dB * 16 + g * 4 + r];
          o[r] = (__bf16)((self * f0 + other * f1) * inv);
        }
        *(bf16x4*)(yp + (dbase ^ sw)) = o;
      }
    }
  }
}

extern "C" void kernel_launch(void* const* d_in, const int* in_sizes, int n_in,
                              void* d_out, int out_size, void* d_ws, size_t ws_size,
                              hipStream_t stream) {
  const float* x     = (const float*)d_in[0];
  const float* cosT  = (const float*)d_in[1];
  const float* sinT  = (const float*)d_in[2];
  const float* v0    = (const float*)d_in[3];
  const float* Wqkv  = (const float*)d_in[4];
  const float* Wproj = (const float*)d_in[5];
  const float* vrl   = (const float*)d_in[6];
  const float* qks   = (const float*)d_in[7];
  float* out = (float*)d_out;

  char* ws = (char*)d_ws;
  unsigned short* xb     = (unsigned short*)ws;                   //  8388608 B (pre-swizzled)
  unsigned short* wqkvb  = (unsigned short*)(ws + 8388608);       //  3145728 B (pre-swizzled)
  unsigned short* wprojb = (unsigned short*)(ws + 11534336);      //  2097152 B (pre-swizzled)
  unsigned short* qb     = (unsigned short*)(ws + 13631488);      //  8388608 B
  unsigned short* kb     = (unsigned short*)(ws + 22020096);      //  2097152 B (d-swizzled)
  unsigned short* vb     = (unsigned short*)(ws + 24117248);      //  8388608 B (V^T swizzled)
  unsigned short* yb     = (unsigned short*)(ws + 32505856);      //  8388608 B (pre-swizzled)

  k_convert_all<<<3328, 256, 0, stream>>>(x, Wqkv, Wproj, xb, wqkvb, wprojb);

  k_gemm_qkv<<<dim3(12, 32), 256, 0, stream>>>(xb, wqkvb, cosT, sinT, v0, vrl, qks, qb, kb, vb);

  k_attn<<<dim3(NH_, 16, B_), 512, 0, stream>>>(qb, kb, vb, yb);

  k_gemm_proj<<<dim3(8, 48), 256, 0, stream>>>(yb, wprojb, v0, out, out + 4194304);
}